// Round 7
// baseline (278.162 us; speedup 1.0000x reference)
//
#include <hip/hip_runtime.h>
#include <hip/hip_bf16.h>

typedef __attribute__((ext_vector_type(8))) short short8x;   // 8 x bf16 (4 VGPR) MFMA A/B frag
typedef __attribute__((ext_vector_type(4))) float f32x4;     // MFMA C/D frag

__device__ __forceinline__ ushort f2bf(float f){
  union { __hip_bfloat16 b; ushort u; } cvt;
  cvt.b = __float2bfloat16(f);                // RNE
  return cvt.u;
}

// ---------------- elementwise fp32 -> bf16 ----------------
__global__ __launch_bounds__(256) void cvt_kernel(const float* __restrict__ in, ushort* __restrict__ out, long n){
  long i = ((long)blockIdx.x * 256 + threadIdx.x) * 4;
  if (i >= n) return;
  float4 v = *(const float4*)(in + i);
  ushort4 o;
  o.x = f2bf(v.x); o.y = f2bf(v.y); o.z = f2bf(v.z); o.w = f2bf(v.w);
  *(ushort4*)(out + i) = o;
}

// ---------------- generic bf16 GEMM: C = A[M,K] * B  with B given as BT[N,K] ----------------
// 128x128 tile, BK=32, 4 waves (2x2), double-buffered LDS staged via global_load_lds(16B).
// XCD-aware block swizzle (T1): all launches have (gridDim.x*gridDim.y) % 8 == 0.
template<int OUTBF>
__global__ __launch_bounds__(256, 3)
void gemm_bt(const ushort* __restrict__ A, const ushort* __restrict__ BT, void* __restrict__ Cv,
             int M, int N, int K, int lda, int ldb, int ldc,
             long aZ, long bZ, long cZ, float scale)
{
  __shared__ __align__(16) ushort As[2][128 * 32];
  __shared__ __align__(16) ushort Bs[2][128 * 32];
  const int z = blockIdx.z;
  const ushort* Ab = A + (long)z * aZ;
  const ushort* Bb = BT + (long)z * bZ;
  const int tid = threadIdx.x, lane = tid & 63, w = tid >> 6;
  const int wm = w >> 1, wn = w & 1;
  const int lq = lane & 15, q4 = lane >> 4;

  int lin = blockIdx.x + gridDim.x * blockIdx.y;
  const int cpx = (gridDim.x * gridDim.y) >> 3;
  lin = (lin & 7) * cpx + (lin >> 3);
  const int bx = lin % gridDim.x, by = lin / gridDim.x;

  const long arow = (long)by * 128, brow = (long)bx * 128;
  const int lr = lane >> 2, lc = (lane & 3) * 8;

  const f32x4 z4 = {0.f, 0.f, 0.f, 0.f};
  f32x4 acc[4][4];
#pragma unroll
  for (int i = 0; i < 4; i++)
#pragma unroll
    for (int j = 0; j < 4; j++) acc[i][j] = z4;

  auto stage = [&](int buf, int k0){
#pragma unroll
    for (int is = 0; is < 2; ++is){
      const int rb = is * 64 + w * 16;
      const ushort* ga = Ab + (arow + rb + lr) * (long)lda + k0 + lc;
      const ushort* gb = Bb + (brow + rb + lr) * (long)ldb + k0 + lc;
      __builtin_amdgcn_global_load_lds((const __attribute__((address_space(1))) void*)ga,
                                       (__attribute__((address_space(3))) void*)&As[buf][rb * 32], 16, 0, 0);
      __builtin_amdgcn_global_load_lds((const __attribute__((address_space(1))) void*)gb,
                                       (__attribute__((address_space(3))) void*)&Bs[buf][rb * 32], 16, 0, 0);
    }
  };

  const int nk = K >> 5;
  stage(0, 0);
  for (int kt = 0; kt < nk; ++kt){
    __syncthreads();
    if (kt + 1 < nk) stage((kt + 1) & 1, (kt + 1) * 32);
    const int buf = kt & 1;
    short8x a[4], b[4];
#pragma unroll
    for (int i = 0; i < 4; i++){
      a[i] = *(const short8x*)&As[buf][(wm * 64 + i * 16 + lq) * 32 + q4 * 8];
      b[i] = *(const short8x*)&Bs[buf][(wn * 64 + i * 16 + lq) * 32 + q4 * 8];
    }
#pragma unroll
    for (int i = 0; i < 4; i++)
#pragma unroll
      for (int j = 0; j < 4; j++)
        acc[i][j] = __builtin_amdgcn_mfma_f32_16x16x32_bf16(a[i], b[j], acc[i][j], 0, 0, 0);
  }

  const long crowb = arow + wm * 64;
  const long ccolb = brow + wn * 64;
#pragma unroll
  for (int i = 0; i < 4; i++)
#pragma unroll
    for (int j = 0; j < 4; j++)
#pragma unroll
      for (int r = 0; r < 4; r++){
        const long row = crowb + i * 16 + q4 * 4 + r;
        const long col = ccolb + j * 16 + lq;
        const float v = acc[i][j][r] * scale;
        if (OUTBF) ((ushort*)Cv)[(long)z * cZ + row * ldc + col] = f2bf(v);
        else       ((float*)Cv)[(long)z * cZ + row * ldc + col] = v;
      }
}

// ---------------- flash attention v7: d=128, causal, 8-wave blocks, KVBLK=64, QBLK=256 ------
// 256 blocks (1/CU), 512 threads (8 waves = 2 waves/SIMD guaranteed co-residency).
// Block: xcd = blk&7 (same-XCD bh grouping, round-5-verified L2 locality), bh = xcd*4 +
// ((blk>>3)&3), qb = blk>>5. Wave w owns q-rows [qb*256 + w*32, +32).
// Heavy block (qb=7) = 32 steps of KVBLK=64 -> wall = 32 steps (was 64).
// Depth-2 LDS double-buffer, counted vmcnt(4); K and V tiles both granule^(row&7) swizzled
// (V rows are now 128B = bank-aligned, needs it too). Per-wave per-si P^T bounce.
__global__ __launch_bounds__(512, 2)
void flash7_kernel(const ushort* __restrict__ q, const ushort* __restrict__ k,
                   const ushort* __restrict__ vT, ushort* __restrict__ attnO)
{
  __shared__ __align__(16) ushort Kb[2][64 * 128];   // [t][d] swizzled granules, 16KB each
  __shared__ __align__(16) ushort Vb[2][128 * 64];   // [d][t] swizzled granules, 16KB each
  __shared__ __align__(16) ushort Pl[8][2][16][72];  // per-wave per-si P^T bounce, 36KB

  const int tid = threadIdx.x, lane = tid & 63, w = tid >> 6;
  const int lq = lane & 15, q4 = lane >> 4;

  const int xcd = blockIdx.x & 7;
  const int bh = xcd * 4 + ((blockIdx.x >> 3) & 3);
  const int qb = blockIdx.x >> 5;
  const int b = bh & 1, h = bh >> 1;

  const int nt = (qb + 1) * 4;              // 64-wide t-tiles staged by this block
  const int wd = qb * 4 + (w >> 1);         // wave's diagonal tile
  const int moff = (w & 1) * 32;            // wave's row offset within the diag tile

  const ushort* kb_ = k + (long)b * 2048 * 2048 + h * 128;        // row t stride 2048
  const ushort* vb_ = vT + (long)h * 128 * 4096 + (long)b * 2048; // row d stride 4096

  // hoisted per-lane staging addresses (t0-independent parts)
  const ushort* kbase[2]; const ushort* vbase[2]; int kofs[2], vofs[2];
#pragma unroll
  for (int is = 0; is < 2; ++is){
    const int ofse = is * 4096 + w * 512;
    const int krow = (ofse >> 7) + (lane >> 4);            // 0..63
    const int kg = (lane & 15) ^ (krow & 7);
    kbase[is] = kb_ + (long)krow * 2048 + kg * 8;
    kofs[is] = ofse;
    const int drow = (ofse >> 6) + (lane >> 3);            // 0..127
    const int vg = (lane & 7) ^ (drow & 7);
    vbase[is] = vb_ + (long)drow * 4096 + vg * 8;
    vofs[is] = ofse;
  }

  auto stage = [&](int buf, int tt){
    const long t0 = (long)tt * 64;
#pragma unroll
    for (int is = 0; is < 2; ++is){
      __builtin_amdgcn_global_load_lds((const __attribute__((address_space(1))) void*)(kbase[is] + t0 * 2048),
          (__attribute__((address_space(3))) void*)&Kb[buf][kofs[is]], 16, 0, 0);
      __builtin_amdgcn_global_load_lds((const __attribute__((address_space(1))) void*)(vbase[is] + t0),
          (__attribute__((address_space(3))) void*)&Vb[buf][vofs[is]], 16, 0, 0);
    }
  };

  const f32x4 z4 = {0.f, 0.f, 0.f, 0.f};

  const int qrow0 = qb * 256 + w * 32;
  const long qgbase = (long)b * 2048 + qrow0;

  // Q B-frags (reused all tiles): s = qrow0+si*16+lq, d = ks*32+q4*8+j
  short8x qf[2][4];
#pragma unroll
  for (int si = 0; si < 2; si++){
    const ushort* qp = q + (qgbase + si * 16 + lq) * 2048 + h * 128 + q4 * 8;
#pragma unroll
    for (int ks = 0; ks < 4; ks++) qf[si][ks] = *(const short8x*)(qp + ks * 32);
  }

  f32x4 oacc[8][2];
#pragma unroll
  for (int dt = 0; dt < 8; dt++){ oacc[dt][0] = z4; oacc[dt][1] = z4; }
  float dsum0 = 0.f, dsum1 = 0.f;

  stage(0, 0);
  stage(1, 1);          // nt >= 4 always

#pragma unroll 1
  for (int tt = 0; tt < nt; ++tt){
    if (tt == nt - 1) asm volatile("s_waitcnt vmcnt(0)" ::: "memory");
    else              asm volatile("s_waitcnt vmcnt(4)" ::: "memory");
    __syncthreads();
    const int cur = tt & 1;

    if (tt <= wd){
      // K A-frags from swizzled LDS: row r = ti*16+lq, granule (ks*4+q4)^(r&7)
      short8x ak[4][4];
#pragma unroll
      for (int ti = 0; ti < 4; ti++){
        const int r = ti * 16 + lq;
        const int rb = r * 128;
        const int rx = r & 7;
#pragma unroll
        for (int ks = 0; ks < 4; ks++)
          ak[ti][ks] = *(const short8x*)&Kb[cur][rb + (((ks * 4 + q4) ^ rx) * 8)];
      }
      f32x4 st[4][2];
#pragma unroll
      for (int ti = 0; ti < 4; ti++){ st[ti][0] = z4; st[ti][1] = z4; }
#pragma unroll
      for (int ks = 0; ks < 4; ks++)
#pragma unroll
        for (int ti = 0; ti < 4; ti++)
#pragma unroll
          for (int si = 0; si < 2; si++)
            st[ti][si] = __builtin_amdgcn_mfma_f32_16x16x32_bf16(ak[ti][ks], qf[si][ks], st[ti][si], 0, 0, 0);

      const bool diag = (tt == wd);
#pragma unroll
      for (int si = 0; si < 2; si++){
        // exp + mask + pack P^T into per-si bounce
#pragma unroll
        for (int ti = 0; ti < 4; ti++){
          ushort4 pb;
#pragma unroll
          for (int r = 0; r < 4; r++){
            const int tl = ti * 16 + q4 * 4 + r;
            float p = __expf(st[ti][si][r]);
            if (diag && tl > moff + si * 16 + lq) p = 0.f;
            if (si) dsum1 += p; else dsum0 += p;
            ((ushort*)&pb)[r] = f2bf(p);
          }
          *(ushort4*)&Pl[w][si][lq][ti * 16 + q4 * 4] = pb;
        }
        asm volatile("s_waitcnt lgkmcnt(0)" ::: "memory");
        __builtin_amdgcn_sched_barrier(0);
        const short8x pf0 = *(const short8x*)&Pl[w][si][lq][q4 * 8];        // t = q4*8+j
        const short8x pf1 = *(const short8x*)&Pl[w][si][lq][32 + q4 * 8];   // t = 32+q4*8+j
        __builtin_amdgcn_sched_barrier(0);
        // PV: O^T[d][s] += V^T[d][t] * P^T[t][s], k=64 in two 32-subtiles
#pragma unroll
        for (int dt = 0; dt < 8; dt++){
          const int r = dt * 16 + lq;
          const int rb = r * 64;
          const int rx = lq & 7;
          const short8x av0 = *(const short8x*)&Vb[cur][rb + (((0 * 4 + q4) ^ rx) * 8)];
          const short8x av1 = *(const short8x*)&Vb[cur][rb + (((1 * 4 + q4) ^ rx) * 8)];
          oacc[dt][si] = __builtin_amdgcn_mfma_f32_16x16x32_bf16(av0, pf0, oacc[dt][si], 0, 0, 0);
          oacc[dt][si] = __builtin_amdgcn_mfma_f32_16x16x32_bf16(av1, pf1, oacc[dt][si], 0, 0, 0);
        }
      }
    }
    __syncthreads();                        // all reads of buf[cur] complete
    if (tt + 2 < nt) stage(cur, tt + 2);    // overwrite buf[cur] = buf[(tt+2)&1]
  }

  dsum0 += __shfl_xor(dsum0, 16); dsum0 += __shfl_xor(dsum0, 32);
  dsum1 += __shfl_xor(dsum1, 16); dsum1 += __shfl_xor(dsum1, 32);
  const float inv0 = 1.f / dsum0, inv1 = 1.f / dsum1;

#pragma unroll
  for (int dt = 0; dt < 8; dt++)
#pragma unroll
    for (int si = 0; si < 2; si++){
      const float inv = si ? inv1 : inv0;
      ushort4 o;
      o.x = f2bf(oacc[dt][si][0] * inv);
      o.y = f2bf(oacc[dt][si][1] * inv);
      o.z = f2bf(oacc[dt][si][2] * inv);
      o.w = f2bf(oacc[dt][si][3] * inv);
      *(ushort4*)(attnO + (qgbase + si * 16 + lq) * 2048 + h * 128 + dt * 16 + q4 * 4) = o;
    }
}

// ---------------- host launcher ----------------
extern "C" void kernel_launch(void* const* d_in, const int* in_sizes, int n_in,
                              void* d_out, int out_size, void* d_ws, size_t ws_size,
                              hipStream_t stream)
{
  const float* x   = (const float*)d_in[0];
  const float* Wd  = (const float*)d_in[1];
  const float* Wuk = (const float*)d_in[2];
  const float* Wuv = (const float*)d_in[3];
  const float* Wq  = (const float*)d_in[4];
  const float* Wo  = (const float*)d_in[5];
  float* out = (float*)d_out;
  ushort* ws = (ushort*)d_ws;

  ushort* xb    = ws + 0L;          // [4096][2048]
  ushort* wdb   = ws + 8388608L;    // [512][2048]
  ushort* wqb   = ws + 9437184L;    // [2048(h,d)][2048(m)]
  ushort* wob   = ws + 13631488L;   // [2048(m)][2048(h,d)]
  ushort* wukb  = ws + 17825792L;   // [2048(h,d)][512(c)]
  ushort* wuvb  = ws + 18874368L;   // [2048(h,d)][512(c)]
  ushort* lat   = ws + 19922944L;   // [4096(b,t)][512(c)]
  ushort* qb    = ws + 22020096L;   // [4096(b,s)][2048(h,d)]
  ushort* kb    = ws + 30408704L;   // [4096(b,t)][2048(h,d)]
  ushort* vTb   = ws + 38797312L;   // [2048(h,d)][4096(b,t)]
  ushort* attnO = ws + 47185920L;   // [4096(b,s)][2048(h,d)]

  cvt_kernel<<<8192, 256, 0, stream>>>(x,   xb,   8388608L);
  cvt_kernel<<<1024, 256, 0, stream>>>(Wd,  wdb,  1048576L);
  cvt_kernel<<<4096, 256, 0, stream>>>(Wq,  wqb,  4194304L);
  cvt_kernel<<<4096, 256, 0, stream>>>(Wo,  wob,  4194304L);
  cvt_kernel<<<1024, 256, 0, stream>>>(Wuk, wukb, 1048576L);
  cvt_kernel<<<1024, 256, 0, stream>>>(Wuv, wuvb, 1048576L);

  // latents = x @ Wd^T : [4096, 512]
  gemm_bt<1><<<dim3(4, 32, 1), 256, 0, stream>>>(xb, wdb, lat, 4096, 512, 2048,
      2048, 2048, 512, 0L, 0L, 0L, 1.0f);
  // q = (x @ Wq^T) / sqrt(128) : [4096, 2048]
  gemm_bt<1><<<dim3(16, 32, 1), 256, 0, stream>>>(xb, wqb, qb, 4096, 2048, 2048,
      2048, 2048, 2048, 0L, 0L, 0L, 0.08838834764831845f);
  // k = lat @ Wuk^T : [4096, 2048]
  gemm_bt<1><<<dim3(16, 32, 1), 256, 0, stream>>>(lat, wukb, kb, 4096, 2048, 512,
      512, 512, 2048, 0L, 0L, 0L, 1.0f);
  // vT = Wuv @ lat^T : [2048(h,d)][4096(b,t)]
  gemm_bt<1><<<dim3(32, 16, 1), 256, 0, stream>>>(wuvb, lat, vTb, 2048, 4096, 512,
      512, 512, 4096, 0L, 0L, 0L, 1.0f);
  // flash attention (causal, d=128): attnO [4096][2048]
  flash7_kernel<<<256, 512, 0, stream>>>(qb, kb, vTb, attnO);
  // out = attnO @ Wo^T : fp32 [4096, 2048]
  gemm_bt<0><<<dim3(16, 32, 1), 256, 0, stream>>>(attnO, wob, out, 4096, 2048, 2048,
      2048, 2048, 2048, 0L, 0L, 0L, 1.0f);
}